// Round 11
// baseline (216.038 us; speedup 1.0000x reference)
//
#include <hip/hip_runtime.h>
#include <hip/hip_fp16.h>

#define U_N 50000
#define I_N 25000
#define D_N 128
#define N_N (U_N + I_N)

#define ROWS_PER_B 256
#define NBUCK 293                       // ceil(75008/256); src>>8 in [0,292]
#define NBLK 512                        // partition blocks (2 per CU)

typedef float f4v __attribute__((ext_vector_type(4)));
typedef float f2v __attribute__((ext_vector_type(2)));
typedef unsigned int u2v __attribute__((ext_vector_type(2)));

// ---- Pass A: per-block coarse histogram + deterministic global totals ----
__global__ __launch_bounds__(256) void part_hist_kernel(const int* __restrict__ src,
                                                        int* __restrict__ hist,
                                                        int* __restrict__ tot,
                                                        int E, int chunk) {
    __shared__ int h[NBUCK];
    int t = threadIdx.x;
    for (int i = t; i < NBUCK; i += 256) h[i] = 0;
    __syncthreads();
    int b = blockIdx.x;
    int s = b * chunk;
    int e = min(E, s + chunk);
    for (int i = s + t; i < e; i += 256)
        atomicAdd(&h[src[i] >> 8], 1);
    __syncthreads();
    for (int i = t; i < NBUCK; i += 256) {
        int c = h[i];
        hist[i * NBLK + b] = c;          // bucket-major: row i contiguous over blocks
        if (c) atomicAdd(&tot[i], c);    // integer sum: order-independent, deterministic
    }
}

// ---- Pass B: separable scans (one kernel) ----
// blocks 0..NBUCK-1: local exclusive scan of hist[B][0..511] -> offs[B][*]
// block NBUCK:       exclusive scan of tot[0..511] -> base[0..293] (base[293]=E)
__global__ __launch_bounds__(256) void scan_kernel(const int* __restrict__ hist,
                                                   const int* __restrict__ tot,
                                                   int* __restrict__ offs,
                                                   int* __restrict__ base) {
    int b = blockIdx.x;
    int t = threadIdx.x;
    int lane = t & 63, wid = t >> 6;
    const int2* in2 = (b < NBUCK) ? (const int2*)(hist + b * NBLK) : (const int2*)tot;
    int2 v = in2[t];                     // elements 2t, 2t+1  (512-wide, zero-padded)
    int p0 = v.x;
    int sum = v.x + v.y;
    int incl = sum;
    for (int off = 1; off < 64; off <<= 1) {
        int u = __shfl_up(incl, off);
        if (lane >= off) incl += u;
    }
    __shared__ int wsum[4];
    if (lane == 63) wsum[wid] = incl;
    __syncthreads();
    int woff = 0;
    for (int w = 0; w < wid; ++w) woff += wsum[w];
    int e0 = woff + incl - sum;          // exclusive prefix of element 2t
    int e1 = e0 + p0;                    // exclusive prefix of element 2t+1
    if (b < NBUCK) {
        int2* out2 = (int2*)(offs + b * NBLK);
        out2[t] = make_int2(e0, e1);
    } else {
        int i0 = 2 * t, i1 = 2 * t + 1;
        if (i0 <= NBUCK) base[i0] = e0;  // base[293] = sum of all tot = E
        if (i1 <= NBUCK) base[i1] = e1;
    }
}

// ---- Pass C: partition packed (srcLow8 | dst) into bucket-contiguous runs ----
__global__ __launch_bounds__(256) void partition_kernel(const int* __restrict__ src,
                                                        const int* __restrict__ dst,
                                                        const int* __restrict__ offs,
                                                        const int* __restrict__ base,
                                                        unsigned int* __restrict__ part,
                                                        int E, int chunk) {
    __shared__ int c[NBUCK];
    int t = threadIdx.x;
    int b = blockIdx.x;
    for (int i = t; i < NBUCK; i += 256)
        c[i] = base[i] + offs[i * NBLK + b];
    __syncthreads();
    int s = b * chunk;
    int e = min(E, s + chunk);
    for (int i = s + t; i < e; i += 256) {
        int sv = src[i];
        int dv = dst[i];
        int pos = atomicAdd(&c[sv >> 8], 1);
        part[pos] = ((unsigned int)(sv & 255) << 24) | (unsigned int)dv;  // dv < 2^24
    }
}

// ---- Pass D: per-bucket fine CSR build + fused x0' init for the bucket's rows ----
__global__ __launch_bounds__(256) void bucket_csr_init_kernel(
    const unsigned int* __restrict__ part, const int* __restrict__ base,
    int* __restrict__ row_ptr, float* __restrict__ dinv, int* __restrict__ csr_dst,
    const f4v* __restrict__ ue, const f4v* __restrict__ ie,
    __half2* __restrict__ x0, int E) {
    int B = blockIdx.x;                  // 0..292
    int t = threadIdx.x;
    int bstart = base[B];
    int bend = base[B + 1];
    __shared__ int cnt_s[ROWS_PER_B];
    __shared__ int base_s[ROWS_PER_B];
    __shared__ float dinv_s[ROWS_PER_B];
    __shared__ int wsum[4];
    cnt_s[t] = 0;
    __syncthreads();
    for (int i = bstart + t; i < bend; i += 256)
        atomicAdd(&cnt_s[part[i] >> 24], 1);
    __syncthreads();
    int v = cnt_s[t];
    int lane = t & 63, wid = t >> 6;
    int incl = v;
    for (int off = 1; off < 64; off <<= 1) {
        int u = __shfl_up(incl, off);
        if (lane >= off) incl += u;
    }
    if (lane == 63) wsum[wid] = incl;
    __syncthreads();
    int woff = 0;
    for (int w = 0; w < wid; ++w) woff += wsum[w];
    int excl = woff + incl - v;
    int gid = B * ROWS_PER_B + t;
    float dv = (v > 0) ? rsqrtf((float)v) : 0.0f;
    if (gid <= N_N) row_ptr[gid] = bstart + excl;   // row 75000 gets E naturally
    if (gid < N_N)  dinv[gid] = dv;
    dinv_s[t] = dv;
    base_s[t] = bstart + excl;
    __syncthreads();
    cnt_s[t] = 0;                        // reuse as fill counters
    __syncthreads();
    for (int i = bstart + t; i < bend; i += 256) {
        unsigned int ev = part[i];
        int lr = ev >> 24;
        int pos = base_s[lr] + atomicAdd(&cnt_s[lr], 1);
        csr_dst[pos] = (int)(ev & 0xFFFFFFu);
    }
    // ---- fused init: x0' = dinv .* concat(ue,ie) fp16 for rows of this bucket ----
    const int NU4 = U_N * D_N / 4;       // float4 count of ue
    const int NT4 = N_N * D_N / 4;
    int base4 = B * (ROWS_PER_B * (D_N / 4));          // 8192 float4 per bucket
    for (int i = t; i < ROWS_PER_B * (D_N / 4); i += 256) {
        int idx = base4 + i;
        if (idx >= NT4) break;
        f4v val = (idx < NU4) ? ue[idx] : ie[idx - NU4];
        float di = dinv_s[i >> 5];       // 32 float4 per row
        __half2 h0 = __floats2half2_rn(di * val.x, di * val.y);
        __half2 h1 = __floats2half2_rn(di * val.z, di * val.w);
        u2v uu = { __builtin_bit_cast(unsigned int, h0),
                   __builtin_bit_cast(unsigned int, h1) };
        *(u2v*)(x0 + 2 * (size_t)idx) = uu;
    }
}

// ------- mid SpMM: one wave per row, unroll 16/8/1 (R8-verified, untouched) -------
// xnext'_i = dinv_i^2 * sum_j x'_j
__global__ __launch_bounds__(256) void spmm_mid_kernel(const __half2* __restrict__ x,
                                                       __half2* __restrict__ xn,
                                                       const float* __restrict__ dinv,
                                                       const int* __restrict__ row_ptr,
                                                       const int* __restrict__ csr_dst) {
    int row = (int)((blockIdx.x * blockDim.x + threadIdx.x) >> 6);
    int lane = threadIdx.x & 63;
    int beg = __builtin_amdgcn_readfirstlane(row_ptr[row]);
    int end = __builtin_amdgcn_readfirstlane(row_ptr[row + 1]);
    float di = dinv[row];
    const __half2* xc = x + lane;       // row j lives at half2 offset j*64
    float accx = 0.0f, accy = 0.0f;
    int k = beg;
    for (; k + 16 <= end; k += 16) {
        int j[16];
        #pragma unroll
        for (int u = 0; u < 16; ++u) j[u] = csr_dst[k + u];
        #pragma unroll
        for (int u = 0; u < 16; ++u) {
            float2 f = __half22float2(xc[(size_t)j[u] * 64]);
            accx += f.x; accy += f.y;
        }
    }
    for (; k + 8 <= end; k += 8) {
        int j[8];
        #pragma unroll
        for (int u = 0; u < 8; ++u) j[u] = csr_dst[k + u];
        #pragma unroll
        for (int u = 0; u < 8; ++u) {
            float2 f = __half22float2(xc[(size_t)j[u] * 64]);
            accx += f.x; accy += f.y;
        }
    }
    for (; k < end; ++k) {
        float2 f = __half22float2(xc[(size_t)csr_dst[k] * 64]);
        accx += f.x; accy += f.y;
    }
    float s = di * di;
    __half2 h = __floats2half2_rn(s * accx, s * accy);
    *(unsigned int*)(xn + (size_t)row * 64 + lane) = __builtin_bit_cast(unsigned int, h);
}

// ------- final SpMM (R8-verified, untouched): y3 + fused average -------
// avg = 0.25*( (x0'+x1'+x2')/dinv + y3 ),  y3 = dinv * sum_j x2'_j
// deg-0 rows: avg = 0.25 * x0 read exactly from ue/ie.
__global__ __launch_bounds__(256) void spmm_final_kernel(const __half2* __restrict__ x2p,
                                                         const __half2* __restrict__ x1p,
                                                         const __half2* __restrict__ x0p,
                                                         const float* __restrict__ ue,
                                                         const float* __restrict__ ie,
                                                         float* __restrict__ avg,
                                                         const float* __restrict__ dinv,
                                                         const int* __restrict__ row_ptr,
                                                         const int* __restrict__ csr_dst) {
    int row = (int)((blockIdx.x * blockDim.x + threadIdx.x) >> 6);
    int lane = threadIdx.x & 63;
    int beg = __builtin_amdgcn_readfirstlane(row_ptr[row]);
    int end = __builtin_amdgcn_readfirstlane(row_ptr[row + 1]);
    float di = dinv[row];
    const __half2* xc = x2p + lane;
    float accx = 0.0f, accy = 0.0f;
    int k = beg;
    for (; k + 16 <= end; k += 16) {
        int j[16];
        #pragma unroll
        for (int u = 0; u < 16; ++u) j[u] = csr_dst[k + u];
        #pragma unroll
        for (int u = 0; u < 16; ++u) {
            float2 f = __half22float2(xc[(size_t)j[u] * 64]);
            accx += f.x; accy += f.y;
        }
    }
    for (; k + 8 <= end; k += 8) {
        int j[8];
        #pragma unroll
        for (int u = 0; u < 8; ++u) j[u] = csr_dst[k + u];
        #pragma unroll
        for (int u = 0; u < 8; ++u) {
            float2 f = __half22float2(xc[(size_t)j[u] * 64]);
            accx += f.x; accy += f.y;
        }
    }
    for (; k < end; ++k) {
        float2 f = __half22float2(xc[(size_t)csr_dst[k] * 64]);
        accx += f.x; accy += f.y;
    }
    f2v a;
    size_t ro = (size_t)row * 64 + lane;
    if (di > 0.0f) {
        float rs = 1.0f / di;
        float2 q0 = __half22float2(x0p[ro]);
        float2 q1 = __half22float2(x1p[ro]);
        float2 q2 = __half22float2(x2p[ro]);
        a.x = 0.25f * (rs * (q0.x + q1.x + q2.x) + di * accx);
        a.y = 0.25f * (rs * (q0.y + q1.y + q2.y) + di * accy);
    } else {
        const float* x0r = (row < U_N) ? (ue + (size_t)row * D_N)
                                       : (ie + (size_t)(row - U_N) * D_N);
        f2v v = *(const f2v*)(x0r + lane * 2);
        a.x = 0.25f * v.x;
        a.y = 0.25f * v.y;
    }
    __builtin_nontemporal_store(a, (f2v*)(avg + (size_t)row * D_N + lane * 2));
}

extern "C" void kernel_launch(void* const* d_in, const int* in_sizes, int n_in,
                              void* d_out, int out_size, void* d_ws, size_t ws_size,
                              hipStream_t stream) {
    const float* ue  = (const float*)d_in[0];
    const float* ie  = (const float*)d_in[1];
    const int* esrc  = (const int*)d_in[2];
    const int* edst  = (const int*)d_in[3];
    float* avg = (float*)d_out;
    const int E = in_sizes[2];
    const int N = N_N;

    // ---- workspace carve-up ----
    char* ws = (char*)d_ws;
    size_t off = 0;
    auto alloc = [&](size_t bytes) -> void* {
        void* p = (void*)(ws + off);
        off += bytes;
        off = (off + 255) & ~((size_t)255);
        return p;
    };
    __half2* x0     = (__half2*)alloc((size_t)N * D_N * sizeof(__half));
    __half2* x1     = (__half2*)alloc((size_t)N * D_N * sizeof(__half));
    __half2* x2     = (__half2*)alloc((size_t)N * D_N * sizeof(__half));
    int*   hist     = (int*)  alloc((size_t)NBUCK * NBLK * sizeof(int));
    int*   offs     = (int*)  alloc((size_t)NBUCK * NBLK * sizeof(int));
    int*   tot      = (int*)  alloc((size_t)512 * sizeof(int));       // zero-padded to 512
    int*   base     = (int*)  alloc((size_t)512 * sizeof(int));       // NBUCK+1 used
    int*   row_ptr  = (int*)  alloc((size_t)(N + 1) * sizeof(int));
    float* dinv     = (float*)alloc((size_t)N * sizeof(float));
    unsigned int* part = (unsigned int*)alloc((size_t)E * sizeof(unsigned int));
    int*   csr_dst  = (int*)  alloc((size_t)E * sizeof(int));

    // ---- build CSR: hist(+tot) -> separable scans -> partition -> bucket CSR ----
    hipMemsetAsync(tot, 0, 512 * sizeof(int), stream);
    int chunk = (E + NBLK - 1) / NBLK;
    part_hist_kernel<<<NBLK, 256, 0, stream>>>(esrc, hist, tot, E, chunk);
    scan_kernel<<<NBUCK + 1, 256, 0, stream>>>(hist, tot, offs, base);
    partition_kernel<<<NBLK, 256, 0, stream>>>(esrc, edst, offs, base, part, E, chunk);
    bucket_csr_init_kernel<<<NBUCK, 256, 0, stream>>>(part, base, row_ptr, dinv, csr_dst,
                                                      (const f4v*)ue, (const f4v*)ie,
                                                      x0, E);

    // ---- layers: one wave per row ----
    int sblocks = (N * 64) / 256;   // 18750, exact
    spmm_mid_kernel<<<sblocks, 256, 0, stream>>>(x0, x1, dinv, row_ptr, csr_dst);
    spmm_mid_kernel<<<sblocks, 256, 0, stream>>>(x1, x2, dinv, row_ptr, csr_dst);
    spmm_final_kernel<<<sblocks, 256, 0, stream>>>(x2, x1, x0, ue, ie, avg, dinv,
                                                   row_ptr, csr_dst);
}

// Round 12
// 209.344 us; speedup vs baseline: 1.0320x; 1.0320x over previous
//
#include <hip/hip_runtime.h>
#include <hip/hip_fp16.h>

#define U_N 50000
#define I_N 25000
#define D_N 128
#define N_N (U_N + I_N)

#define ROWS_PER_B 256
#define NBUCK 293                       // ceil(75008/256); src>>8 in [0,292]
#define NBLK 512                        // partition blocks (2 per CU)
#define SN (NBUCK * NBLK)               // 150016 scan elements

#define SCAN_ELEMS_PER_BLOCK 1024       // 256 threads x int4
#define NUM_SCAN_BLOCKS ((SN + SCAN_ELEMS_PER_BLOCK - 1) / SCAN_ELEMS_PER_BLOCK)  // 147
#define SN_PAD (NUM_SCAN_BLOCKS * SCAN_ELEMS_PER_BLOCK)                            // 150528

typedef float f4v __attribute__((ext_vector_type(4)));
typedef float f2v __attribute__((ext_vector_type(2)));
typedef unsigned int u2v __attribute__((ext_vector_type(2)));

// ---- Pass A: per-block coarse histogram (293 buckets); block 0 zeroes pad ----
__global__ __launch_bounds__(256) void part_hist_kernel(const int* __restrict__ src,
                                                        int* __restrict__ hist,
                                                        int E, int chunk) {
    __shared__ int h[NBUCK];
    int t = threadIdx.x;
    for (int i = t; i < NBUCK; i += 256) h[i] = 0;
    __syncthreads();
    int b = blockIdx.x;
    int s = b * chunk;
    int e = min(E, s + chunk);
    for (int i = s + t; i < e; i += 256)
        atomicAdd(&h[src[i] >> 8], 1);
    __syncthreads();
    for (int i = t; i < NBUCK; i += 256)
        hist[i * NBLK + b] = h[i];       // bucket-major layout for the scan
    if (b == 0)
        for (int i = SN + t; i < SN_PAD; i += 256) hist[i] = 0;   // pad for int4 scan
}

// -------- scan phase A: per-block sums (1024 elems / block) --------
__global__ __launch_bounds__(256) void block_sums_kernel(const int4* __restrict__ cnt4,
                                                         int* __restrict__ bsums) {
    int t = threadIdx.x;
    int idx = blockIdx.x * 256 + t;
    int4 v = cnt4[idx];
    int s = v.x + v.y + v.z + v.w;
    for (int off = 32; off; off >>= 1) s += __shfl_down(s, off);
    __shared__ int wsum[4];
    int wid = t >> 6, lane = t & 63;
    if (lane == 0) wsum[wid] = s;
    __syncthreads();
    if (t == 0) bsums[blockIdx.x] = wsum[0] + wsum[1] + wsum[2] + wsum[3];
}

// -------- scan phase B: scan the 147 block sums (one block, 256-wide) --------
__global__ __launch_bounds__(256) void scan_bsums_kernel(const int* __restrict__ bsums,
                                                         int* __restrict__ boffs, int nb) {
    __shared__ int sd[256];
    int t = threadIdx.x;
    int v = (t < nb) ? bsums[t] : 0;
    sd[t] = v;
    __syncthreads();
    for (int off = 1; off < 256; off <<= 1) {
        int add = (t >= off) ? sd[t - off] : 0;
        __syncthreads();
        sd[t] += add;
        __syncthreads();
    }
    if (t < nb) boffs[t] = sd[t] - v;   // exclusive
}

// -------- scan phase C: local scan + writeback of exclusive offsets --------
__global__ __launch_bounds__(256) void local_scan_offs_kernel(const int4* __restrict__ cnt4,
                                                              const int* __restrict__ boffs,
                                                              int4* __restrict__ offs4) {
    int t = threadIdx.x;
    int gidx = blockIdx.x * 256 + t;
    int4 v = cnt4[gidx];
    int p0 = v.x, p1 = p0 + v.y, p2 = p1 + v.z, p3 = p2 + v.w;
    int tsum = p3;
    int lane = t & 63, wid = t >> 6;
    int incl = tsum;
    for (int off = 1; off < 64; off <<= 1) {
        int u = __shfl_up(incl, off);
        if (lane >= off) incl += u;
    }
    int lexcl = incl - tsum;
    __shared__ int wsum[4];
    if (lane == 63) wsum[wid] = incl;
    __syncthreads();
    int woff = 0;
    for (int w = 0; w < wid; ++w) woff += wsum[w];
    int base = boffs[blockIdx.x] + woff + lexcl;
    int4 o;
    o.x = base; o.y = base + p0; o.z = base + p1; o.w = base + p2;
    offs4[gidx] = o;
}

// ---- Pass C: partition packed (srcLow8 | dst) into bucket-contiguous runs ----
__global__ __launch_bounds__(256) void partition_kernel(const int* __restrict__ src,
                                                        const int* __restrict__ dst,
                                                        const int* __restrict__ offs,
                                                        unsigned int* __restrict__ part,
                                                        int E, int chunk) {
    __shared__ int c[NBUCK];
    int t = threadIdx.x;
    int b = blockIdx.x;
    for (int i = t; i < NBUCK; i += 256) c[i] = offs[i * NBLK + b];
    __syncthreads();
    int s = b * chunk;
    int e = min(E, s + chunk);
    for (int i = s + t; i < e; i += 256) {
        int sv = src[i];
        int dv = dst[i];
        int pos = atomicAdd(&c[sv >> 8], 1);
        part[pos] = ((unsigned int)(sv & 255) << 24) | (unsigned int)dv;  // dv < 2^24
    }
}

// ---- Pass D: per-bucket fine CSR build + fused x0' init for the bucket's rows ----
__global__ __launch_bounds__(256) void bucket_csr_init_kernel(
    const unsigned int* __restrict__ part, const int* __restrict__ offs,
    int* __restrict__ row_ptr, float* __restrict__ dinv, int* __restrict__ csr_dst,
    const f4v* __restrict__ ue, const f4v* __restrict__ ie,
    __half2* __restrict__ x0, int E) {
    int B = blockIdx.x;                  // 0..292
    int t = threadIdx.x;
    int bstart = offs[B * NBLK];
    int bend = (B + 1 < NBUCK) ? offs[(B + 1) * NBLK] : E;
    __shared__ int cnt_s[ROWS_PER_B];
    __shared__ int base_s[ROWS_PER_B];
    __shared__ float dinv_s[ROWS_PER_B];
    __shared__ int wsum[4];
    cnt_s[t] = 0;
    __syncthreads();
    for (int i = bstart + t; i < bend; i += 256)
        atomicAdd(&cnt_s[part[i] >> 24], 1);
    __syncthreads();
    int v = cnt_s[t];
    int lane = t & 63, wid = t >> 6;
    int incl = v;
    for (int off = 1; off < 64; off <<= 1) {
        int u = __shfl_up(incl, off);
        if (lane >= off) incl += u;
    }
    if (lane == 63) wsum[wid] = incl;
    __syncthreads();
    int woff = 0;
    for (int w = 0; w < wid; ++w) woff += wsum[w];
    int excl = woff + incl - v;
    int gid = B * ROWS_PER_B + t;
    float dv = (v > 0) ? rsqrtf((float)v) : 0.0f;
    if (gid <= N_N) row_ptr[gid] = bstart + excl;   // row 75000 gets E naturally
    if (gid < N_N)  dinv[gid] = dv;
    dinv_s[t] = dv;
    base_s[t] = bstart + excl;
    __syncthreads();
    cnt_s[t] = 0;                        // reuse as fill counters
    __syncthreads();
    for (int i = bstart + t; i < bend; i += 256) {
        unsigned int ev = part[i];
        int lr = ev >> 24;
        int pos = base_s[lr] + atomicAdd(&cnt_s[lr], 1);
        csr_dst[pos] = (int)(ev & 0xFFFFFFu);
    }
    // ---- fused init: x0' = dinv .* concat(ue,ie) fp16 for rows of this bucket ----
    const int NU4 = U_N * D_N / 4;       // float4 count of ue
    const int NT4 = N_N * D_N / 4;
    int base4 = B * (ROWS_PER_B * (D_N / 4));          // 8192 float4 per bucket
    for (int i = t; i < ROWS_PER_B * (D_N / 4); i += 256) {
        int idx = base4 + i;
        if (idx >= NT4) break;
        f4v val = (idx < NU4) ? ue[idx] : ie[idx - NU4];
        float di = dinv_s[i >> 5];       // 32 float4 per row
        __half2 h0 = __floats2half2_rn(di * val.x, di * val.y);
        __half2 h1 = __floats2half2_rn(di * val.z, di * val.w);
        u2v uu = { __builtin_bit_cast(unsigned int, h0),
                   __builtin_bit_cast(unsigned int, h1) };
        *(u2v*)(x0 + 2 * (size_t)idx) = uu;
    }
}

// ------- mid SpMM: one wave per row, unroll 16/8/1 (R8-verified, untouched) -------
// xnext'_i = dinv_i^2 * sum_j x'_j
__global__ __launch_bounds__(256) void spmm_mid_kernel(const __half2* __restrict__ x,
                                                       __half2* __restrict__ xn,
                                                       const float* __restrict__ dinv,
                                                       const int* __restrict__ row_ptr,
                                                       const int* __restrict__ csr_dst) {
    int row = (int)((blockIdx.x * blockDim.x + threadIdx.x) >> 6);
    int lane = threadIdx.x & 63;
    int beg = __builtin_amdgcn_readfirstlane(row_ptr[row]);
    int end = __builtin_amdgcn_readfirstlane(row_ptr[row + 1]);
    float di = dinv[row];
    const __half2* xc = x + lane;       // row j lives at half2 offset j*64
    float accx = 0.0f, accy = 0.0f;
    int k = beg;
    for (; k + 16 <= end; k += 16) {
        int j[16];
        #pragma unroll
        for (int u = 0; u < 16; ++u) j[u] = csr_dst[k + u];
        #pragma unroll
        for (int u = 0; u < 16; ++u) {
            float2 f = __half22float2(xc[(size_t)j[u] * 64]);
            accx += f.x; accy += f.y;
        }
    }
    for (; k + 8 <= end; k += 8) {
        int j[8];
        #pragma unroll
        for (int u = 0; u < 8; ++u) j[u] = csr_dst[k + u];
        #pragma unroll
        for (int u = 0; u < 8; ++u) {
            float2 f = __half22float2(xc[(size_t)j[u] * 64]);
            accx += f.x; accy += f.y;
        }
    }
    for (; k < end; ++k) {
        float2 f = __half22float2(xc[(size_t)csr_dst[k] * 64]);
        accx += f.x; accy += f.y;
    }
    float s = di * di;
    __half2 h = __floats2half2_rn(s * accx, s * accy);
    *(unsigned int*)(xn + (size_t)row * 64 + lane) = __builtin_bit_cast(unsigned int, h);
}

// ------- final SpMM (R8-verified, untouched): y3 + fused average -------
// avg = 0.25*( (x0'+x1'+x2')/dinv + y3 ),  y3 = dinv * sum_j x2'_j
// deg-0 rows: avg = 0.25 * x0 read exactly from ue/ie.
__global__ __launch_bounds__(256) void spmm_final_kernel(const __half2* __restrict__ x2p,
                                                         const __half2* __restrict__ x1p,
                                                         const __half2* __restrict__ x0p,
                                                         const float* __restrict__ ue,
                                                         const float* __restrict__ ie,
                                                         float* __restrict__ avg,
                                                         const float* __restrict__ dinv,
                                                         const int* __restrict__ row_ptr,
                                                         const int* __restrict__ csr_dst) {
    int row = (int)((blockIdx.x * blockDim.x + threadIdx.x) >> 6);
    int lane = threadIdx.x & 63;
    int beg = __builtin_amdgcn_readfirstlane(row_ptr[row]);
    int end = __builtin_amdgcn_readfirstlane(row_ptr[row + 1]);
    float di = dinv[row];
    const __half2* xc = x2p + lane;
    float accx = 0.0f, accy = 0.0f;
    int k = beg;
    for (; k + 16 <= end; k += 16) {
        int j[16];
        #pragma unroll
        for (int u = 0; u < 16; ++u) j[u] = csr_dst[k + u];
        #pragma unroll
        for (int u = 0; u < 16; ++u) {
            float2 f = __half22float2(xc[(size_t)j[u] * 64]);
            accx += f.x; accy += f.y;
        }
    }
    for (; k + 8 <= end; k += 8) {
        int j[8];
        #pragma unroll
        for (int u = 0; u < 8; ++u) j[u] = csr_dst[k + u];
        #pragma unroll
        for (int u = 0; u < 8; ++u) {
            float2 f = __half22float2(xc[(size_t)j[u] * 64]);
            accx += f.x; accy += f.y;
        }
    }
    for (; k < end; ++k) {
        float2 f = __half22float2(xc[(size_t)csr_dst[k] * 64]);
        accx += f.x; accy += f.y;
    }
    f2v a;
    size_t ro = (size_t)row * 64 + lane;
    if (di > 0.0f) {
        float rs = 1.0f / di;
        float2 q0 = __half22float2(x0p[ro]);
        float2 q1 = __half22float2(x1p[ro]);
        float2 q2 = __half22float2(x2p[ro]);
        a.x = 0.25f * (rs * (q0.x + q1.x + q2.x) + di * accx);
        a.y = 0.25f * (rs * (q0.y + q1.y + q2.y) + di * accy);
    } else {
        const float* x0r = (row < U_N) ? (ue + (size_t)row * D_N)
                                       : (ie + (size_t)(row - U_N) * D_N);
        f2v v = *(const f2v*)(x0r + lane * 2);
        a.x = 0.25f * v.x;
        a.y = 0.25f * v.y;
    }
    __builtin_nontemporal_store(a, (f2v*)(avg + (size_t)row * D_N + lane * 2));
}

extern "C" void kernel_launch(void* const* d_in, const int* in_sizes, int n_in,
                              void* d_out, int out_size, void* d_ws, size_t ws_size,
                              hipStream_t stream) {
    const float* ue  = (const float*)d_in[0];
    const float* ie  = (const float*)d_in[1];
    const int* esrc  = (const int*)d_in[2];
    const int* edst  = (const int*)d_in[3];
    float* avg = (float*)d_out;
    const int E = in_sizes[2];
    const int N = N_N;

    // ---- workspace carve-up ----
    char* ws = (char*)d_ws;
    size_t off = 0;
    auto alloc = [&](size_t bytes) -> void* {
        void* p = (void*)(ws + off);
        off += bytes;
        off = (off + 255) & ~((size_t)255);
        return p;
    };
    __half2* x0     = (__half2*)alloc((size_t)N * D_N * sizeof(__half));
    __half2* x1     = (__half2*)alloc((size_t)N * D_N * sizeof(__half));
    __half2* x2     = (__half2*)alloc((size_t)N * D_N * sizeof(__half));
    int*   hist     = (int*)  alloc((size_t)SN_PAD * sizeof(int));
    int*   offs     = (int*)  alloc((size_t)SN_PAD * sizeof(int));
    int*   row_ptr  = (int*)  alloc((size_t)(N + 1) * sizeof(int));
    float* dinv     = (float*)alloc((size_t)N * sizeof(float));
    int*   bsums    = (int*)  alloc((size_t)NUM_SCAN_BLOCKS * sizeof(int));
    int*   boffs    = (int*)  alloc((size_t)NUM_SCAN_BLOCKS * sizeof(int));
    unsigned int* part = (unsigned int*)alloc((size_t)E * sizeof(unsigned int));
    int*   csr_dst  = (int*)  alloc((size_t)E * sizeof(int));

    // ---- build CSR via two-level radix partition (no memset, no init launch) ----
    int chunk = (E + NBLK - 1) / NBLK;
    part_hist_kernel<<<NBLK, 256, 0, stream>>>(esrc, hist, E, chunk);
    block_sums_kernel<<<NUM_SCAN_BLOCKS, 256, 0, stream>>>((const int4*)hist, bsums);
    scan_bsums_kernel<<<1, 256, 0, stream>>>(bsums, boffs, NUM_SCAN_BLOCKS);
    local_scan_offs_kernel<<<NUM_SCAN_BLOCKS, 256, 0, stream>>>((const int4*)hist, boffs,
                                                                (int4*)offs);
    partition_kernel<<<NBLK, 256, 0, stream>>>(esrc, edst, offs, part, E, chunk);
    bucket_csr_init_kernel<<<NBUCK, 256, 0, stream>>>(part, offs, row_ptr, dinv, csr_dst,
                                                      (const f4v*)ue, (const f4v*)ie,
                                                      x0, E);

    // ---- layers: one wave per row ----
    int sblocks = (N * 64) / 256;   // 18750, exact
    spmm_mid_kernel<<<sblocks, 256, 0, stream>>>(x0, x1, dinv, row_ptr, csr_dst);
    spmm_mid_kernel<<<sblocks, 256, 0, stream>>>(x1, x2, dinv, row_ptr, csr_dst);
    spmm_final_kernel<<<sblocks, 256, 0, stream>>>(x2, x1, x0, ue, ie, avg, dinv,
                                                   row_ptr, csr_dst);
}

// Round 13
// 205.171 us; speedup vs baseline: 1.0530x; 1.0203x over previous
//
#include <hip/hip_runtime.h>
#include <hip/hip_fp16.h>

#define U_N 50000
#define I_N 25000
#define D_N 128
#define N_N (U_N + I_N)

#define ROWS_PER_B 256
#define NBUCK 293                       // ceil(75008/256); src>>8 in [0,292]
#define NBLK 512                        // partition blocks (2 per CU)
#define SN (NBUCK * NBLK)               // 150016 scan elements

#define SCAN_ELEMS_PER_BLOCK 1024       // 256 threads x int4
#define NUM_SCAN_BLOCKS ((SN + SCAN_ELEMS_PER_BLOCK - 1) / SCAN_ELEMS_PER_BLOCK)  // 147
#define SN_PAD (NUM_SCAN_BLOCKS * SCAN_ELEMS_PER_BLOCK)                            // 150528

typedef float f4v __attribute__((ext_vector_type(4)));
typedef float f2v __attribute__((ext_vector_type(2)));
typedef unsigned int u2v __attribute__((ext_vector_type(2)));

// ---- Pass A: per-block coarse histogram (293 buckets); block 0 zeroes pad ----
__global__ __launch_bounds__(256) void part_hist_kernel(const int* __restrict__ src,
                                                        int* __restrict__ hist,
                                                        int E, int chunk) {
    __shared__ int h[NBUCK];
    int t = threadIdx.x;
    for (int i = t; i < NBUCK; i += 256) h[i] = 0;
    __syncthreads();
    int b = blockIdx.x;
    int s = b * chunk;
    int e = min(E, s + chunk);
    for (int i = s + t; i < e; i += 256)
        atomicAdd(&h[src[i] >> 8], 1);
    __syncthreads();
    for (int i = t; i < NBUCK; i += 256)
        hist[i * NBLK + b] = h[i];       // bucket-major layout for the scan
    if (b == 0)
        for (int i = SN + t; i < SN_PAD; i += 256) hist[i] = 0;   // pad for int4 scan
}

// -------- scan phase A: per-block sums (1024 elems / block) --------
__global__ __launch_bounds__(256) void block_sums_kernel(const int4* __restrict__ cnt4,
                                                         int* __restrict__ bsums) {
    int t = threadIdx.x;
    int idx = blockIdx.x * 256 + t;
    int4 v = cnt4[idx];
    int s = v.x + v.y + v.z + v.w;
    for (int off = 32; off; off >>= 1) s += __shfl_down(s, off);
    __shared__ int wsum[4];
    int wid = t >> 6, lane = t & 63;
    if (lane == 0) wsum[wid] = s;
    __syncthreads();
    if (t == 0) bsums[blockIdx.x] = wsum[0] + wsum[1] + wsum[2] + wsum[3];
}

// -------- scan phase B: scan the 147 block sums (one block, 256-wide) --------
__global__ __launch_bounds__(256) void scan_bsums_kernel(const int* __restrict__ bsums,
                                                         int* __restrict__ boffs, int nb) {
    __shared__ int sd[256];
    int t = threadIdx.x;
    int v = (t < nb) ? bsums[t] : 0;
    sd[t] = v;
    __syncthreads();
    for (int off = 1; off < 256; off <<= 1) {
        int add = (t >= off) ? sd[t - off] : 0;
        __syncthreads();
        sd[t] += add;
        __syncthreads();
    }
    if (t < nb) boffs[t] = sd[t] - v;   // exclusive
}

// -------- scan phase C: local scan + writeback of exclusive offsets --------
__global__ __launch_bounds__(256) void local_scan_offs_kernel(const int4* __restrict__ cnt4,
                                                              const int* __restrict__ boffs,
                                                              int4* __restrict__ offs4) {
    int t = threadIdx.x;
    int gidx = blockIdx.x * 256 + t;
    int4 v = cnt4[gidx];
    int p0 = v.x, p1 = p0 + v.y, p2 = p1 + v.z, p3 = p2 + v.w;
    int tsum = p3;
    int lane = t & 63, wid = t >> 6;
    int incl = tsum;
    for (int off = 1; off < 64; off <<= 1) {
        int u = __shfl_up(incl, off);
        if (lane >= off) incl += u;
    }
    int lexcl = incl - tsum;
    __shared__ int wsum[4];
    if (lane == 63) wsum[wid] = incl;
    __syncthreads();
    int woff = 0;
    for (int w = 0; w < wid; ++w) woff += wsum[w];
    int base = boffs[blockIdx.x] + woff + lexcl;
    int4 o;
    o.x = base; o.y = base + p0; o.z = base + p1; o.w = base + p2;
    offs4[gidx] = o;
}

// ---- Pass C: partition packed (srcLow8 | dst) into bucket-contiguous runs ----
__global__ __launch_bounds__(256) void partition_kernel(const int* __restrict__ src,
                                                        const int* __restrict__ dst,
                                                        const int* __restrict__ offs,
                                                        unsigned int* __restrict__ part,
                                                        int E, int chunk) {
    __shared__ int c[NBUCK];
    int t = threadIdx.x;
    int b = blockIdx.x;
    for (int i = t; i < NBUCK; i += 256) c[i] = offs[i * NBLK + b];
    __syncthreads();
    int s = b * chunk;
    int e = min(E, s + chunk);
    for (int i = s + t; i < e; i += 256) {
        int sv = src[i];
        int dv = dst[i];
        int pos = atomicAdd(&c[sv >> 8], 1);
        part[pos] = ((unsigned int)(sv & 255) << 24) | (unsigned int)dv;  // dv < 2^24
    }
}

// ---- Pass D: per-bucket fine CSR build (CSR only — init un-fused) ----
__global__ __launch_bounds__(256) void bucket_csr_kernel(
    const unsigned int* __restrict__ part, const int* __restrict__ offs,
    int* __restrict__ row_ptr, float* __restrict__ dinv, int* __restrict__ csr_dst,
    int E) {
    int B = blockIdx.x;                  // 0..292
    int t = threadIdx.x;
    int bstart = offs[B * NBLK];
    int bend = (B + 1 < NBUCK) ? offs[(B + 1) * NBLK] : E;
    __shared__ int cnt_s[ROWS_PER_B];
    __shared__ int base_s[ROWS_PER_B];
    __shared__ int wsum[4];
    cnt_s[t] = 0;
    __syncthreads();
    for (int i = bstart + t; i < bend; i += 256)
        atomicAdd(&cnt_s[part[i] >> 24], 1);
    __syncthreads();
    int v = cnt_s[t];
    int lane = t & 63, wid = t >> 6;
    int incl = v;
    for (int off = 1; off < 64; off <<= 1) {
        int u = __shfl_up(incl, off);
        if (lane >= off) incl += u;
    }
    if (lane == 63) wsum[wid] = incl;
    __syncthreads();
    int woff = 0;
    for (int w = 0; w < wid; ++w) woff += wsum[w];
    int excl = woff + incl - v;
    int gid = B * ROWS_PER_B + t;
    float dv = (v > 0) ? rsqrtf((float)v) : 0.0f;
    if (gid <= N_N) row_ptr[gid] = bstart + excl;   // row 75000 gets E naturally
    if (gid < N_N)  dinv[gid] = dv;
    base_s[t] = bstart + excl;
    __syncthreads();
    cnt_s[t] = 0;                        // reuse as fill counters
    __syncthreads();
    for (int i = bstart + t; i < bend; i += 256) {
        unsigned int ev = part[i];
        int lr = ev >> 24;
        int pos = base_s[lr] + atomicAdd(&cnt_s[lr], 1);
        csr_dst[pos] = (int)(ev & 0xFFFFFFu);
    }
}

// -- init (standalone, R6-verified): x0' = dinv .* concat(ue,ie) in fp16 --
__global__ __launch_bounds__(256) void init_kernel(const f4v* __restrict__ ue,
                                                   const f4v* __restrict__ ie,
                                                   const float* __restrict__ dinv,
                                                   __half2* __restrict__ x) {
    const int NU4 = U_N * D_N / 4;
    const int NT4 = N_N * D_N / 4;
    int i = blockIdx.x * blockDim.x + threadIdx.x;
    if (i >= NT4) return;
    f4v v = (i < NU4) ? ue[i] : ie[i - NU4];
    float di = dinv[i >> 5];            // 128 floats/row = 32 float4/row
    __half2 h0 = __floats2half2_rn(di * v.x, di * v.y);
    __half2 h1 = __floats2half2_rn(di * v.z, di * v.w);
    u2v uu = { __builtin_bit_cast(unsigned int, h0),
               __builtin_bit_cast(unsigned int, h1) };
    *(u2v*)(x + 2 * (size_t)i) = uu;
}

// ------- mid SpMM: one wave per row, unroll 16/8/1 (R8-verified, untouched) -------
// xnext'_i = dinv_i^2 * sum_j x'_j
__global__ __launch_bounds__(256) void spmm_mid_kernel(const __half2* __restrict__ x,
                                                       __half2* __restrict__ xn,
                                                       const float* __restrict__ dinv,
                                                       const int* __restrict__ row_ptr,
                                                       const int* __restrict__ csr_dst) {
    int row = (int)((blockIdx.x * blockDim.x + threadIdx.x) >> 6);
    int lane = threadIdx.x & 63;
    int beg = __builtin_amdgcn_readfirstlane(row_ptr[row]);
    int end = __builtin_amdgcn_readfirstlane(row_ptr[row + 1]);
    float di = dinv[row];
    const __half2* xc = x + lane;       // row j lives at half2 offset j*64
    float accx = 0.0f, accy = 0.0f;
    int k = beg;
    for (; k + 16 <= end; k += 16) {
        int j[16];
        #pragma unroll
        for (int u = 0; u < 16; ++u) j[u] = csr_dst[k + u];
        #pragma unroll
        for (int u = 0; u < 16; ++u) {
            float2 f = __half22float2(xc[(size_t)j[u] * 64]);
            accx += f.x; accy += f.y;
        }
    }
    for (; k + 8 <= end; k += 8) {
        int j[8];
        #pragma unroll
        for (int u = 0; u < 8; ++u) j[u] = csr_dst[k + u];
        #pragma unroll
        for (int u = 0; u < 8; ++u) {
            float2 f = __half22float2(xc[(size_t)j[u] * 64]);
            accx += f.x; accy += f.y;
        }
    }
    for (; k < end; ++k) {
        float2 f = __half22float2(xc[(size_t)csr_dst[k] * 64]);
        accx += f.x; accy += f.y;
    }
    float s = di * di;
    __half2 h = __floats2half2_rn(s * accx, s * accy);
    *(unsigned int*)(xn + (size_t)row * 64 + lane) = __builtin_bit_cast(unsigned int, h);
}

// ------- final SpMM (R8-verified, untouched): y3 + fused average -------
// avg = 0.25*( (x0'+x1'+x2')/dinv + y3 ),  y3 = dinv * sum_j x2'_j
// deg-0 rows: avg = 0.25 * x0 read exactly from ue/ie.
__global__ __launch_bounds__(256) void spmm_final_kernel(const __half2* __restrict__ x2p,
                                                         const __half2* __restrict__ x1p,
                                                         const __half2* __restrict__ x0p,
                                                         const float* __restrict__ ue,
                                                         const float* __restrict__ ie,
                                                         float* __restrict__ avg,
                                                         const float* __restrict__ dinv,
                                                         const int* __restrict__ row_ptr,
                                                         const int* __restrict__ csr_dst) {
    int row = (int)((blockIdx.x * blockDim.x + threadIdx.x) >> 6);
    int lane = threadIdx.x & 63;
    int beg = __builtin_amdgcn_readfirstlane(row_ptr[row]);
    int end = __builtin_amdgcn_readfirstlane(row_ptr[row + 1]);
    float di = dinv[row];
    const __half2* xc = x2p + lane;
    float accx = 0.0f, accy = 0.0f;
    int k = beg;
    for (; k + 16 <= end; k += 16) {
        int j[16];
        #pragma unroll
        for (int u = 0; u < 16; ++u) j[u] = csr_dst[k + u];
        #pragma unroll
        for (int u = 0; u < 16; ++u) {
            float2 f = __half22float2(xc[(size_t)j[u] * 64]);
            accx += f.x; accy += f.y;
        }
    }
    for (; k + 8 <= end; k += 8) {
        int j[8];
        #pragma unroll
        for (int u = 0; u < 8; ++u) j[u] = csr_dst[k + u];
        #pragma unroll
        for (int u = 0; u < 8; ++u) {
            float2 f = __half22float2(xc[(size_t)j[u] * 64]);
            accx += f.x; accy += f.y;
        }
    }
    for (; k < end; ++k) {
        float2 f = __half22float2(xc[(size_t)csr_dst[k] * 64]);
        accx += f.x; accy += f.y;
    }
    f2v a;
    size_t ro = (size_t)row * 64 + lane;
    if (di > 0.0f) {
        float rs = 1.0f / di;
        float2 q0 = __half22float2(x0p[ro]);
        float2 q1 = __half22float2(x1p[ro]);
        float2 q2 = __half22float2(x2p[ro]);
        a.x = 0.25f * (rs * (q0.x + q1.x + q2.x) + di * accx);
        a.y = 0.25f * (rs * (q0.y + q1.y + q2.y) + di * accy);
    } else {
        const float* x0r = (row < U_N) ? (ue + (size_t)row * D_N)
                                       : (ie + (size_t)(row - U_N) * D_N);
        f2v v = *(const f2v*)(x0r + lane * 2);
        a.x = 0.25f * v.x;
        a.y = 0.25f * v.y;
    }
    __builtin_nontemporal_store(a, (f2v*)(avg + (size_t)row * D_N + lane * 2));
}

extern "C" void kernel_launch(void* const* d_in, const int* in_sizes, int n_in,
                              void* d_out, int out_size, void* d_ws, size_t ws_size,
                              hipStream_t stream) {
    const float* ue  = (const float*)d_in[0];
    const float* ie  = (const float*)d_in[1];
    const int* esrc  = (const int*)d_in[2];
    const int* edst  = (const int*)d_in[3];
    float* avg = (float*)d_out;
    const int E = in_sizes[2];
    const int N = N_N;

    // ---- workspace carve-up ----
    char* ws = (char*)d_ws;
    size_t off = 0;
    auto alloc = [&](size_t bytes) -> void* {
        void* p = (void*)(ws + off);
        off += bytes;
        off = (off + 255) & ~((size_t)255);
        return p;
    };
    __half2* x0     = (__half2*)alloc((size_t)N * D_N * sizeof(__half));
    __half2* x1     = (__half2*)alloc((size_t)N * D_N * sizeof(__half));
    __half2* x2     = (__half2*)alloc((size_t)N * D_N * sizeof(__half));
    int*   hist     = (int*)  alloc((size_t)SN_PAD * sizeof(int));
    int*   offs     = (int*)  alloc((size_t)SN_PAD * sizeof(int));
    int*   row_ptr  = (int*)  alloc((size_t)(N + 1) * sizeof(int));
    float* dinv     = (float*)alloc((size_t)N * sizeof(float));
    int*   bsums    = (int*)  alloc((size_t)NUM_SCAN_BLOCKS * sizeof(int));
    int*   boffs    = (int*)  alloc((size_t)NUM_SCAN_BLOCKS * sizeof(int));
    unsigned int* part = (unsigned int*)alloc((size_t)E * sizeof(unsigned int));
    int*   csr_dst  = (int*)  alloc((size_t)E * sizeof(int));

    // ---- build CSR via two-level radix partition ----
    int chunk = (E + NBLK - 1) / NBLK;
    part_hist_kernel<<<NBLK, 256, 0, stream>>>(esrc, hist, E, chunk);
    block_sums_kernel<<<NUM_SCAN_BLOCKS, 256, 0, stream>>>((const int4*)hist, bsums);
    scan_bsums_kernel<<<1, 256, 0, stream>>>(bsums, boffs, NUM_SCAN_BLOCKS);
    local_scan_offs_kernel<<<NUM_SCAN_BLOCKS, 256, 0, stream>>>((const int4*)hist, boffs,
                                                                (int4*)offs);
    partition_kernel<<<NBLK, 256, 0, stream>>>(esrc, edst, offs, part, E, chunk);
    bucket_csr_kernel<<<NBUCK, 256, 0, stream>>>(part, offs, row_ptr, dinv, csr_dst, E);

    // ---- init x0' with full-device parallelism ----
    const int NT4 = N * D_N / 4;
    init_kernel<<<(NT4 + 255) / 256, 256, 0, stream>>>(
        (const f4v*)ue, (const f4v*)ie, dinv, x0);

    // ---- layers: one wave per row ----
    int sblocks = (N * 64) / 256;   // 18750, exact
    spmm_mid_kernel<<<sblocks, 256, 0, stream>>>(x0, x1, dinv, row_ptr, csr_dst);
    spmm_mid_kernel<<<sblocks, 256, 0, stream>>>(x1, x2, dinv, row_ptr, csr_dst);
    spmm_final_kernel<<<sblocks, 256, 0, stream>>>(x2, x1, x0, ue, ie, avg, dinv,
                                                   row_ptr, csr_dst);
}

// Round 14
// 203.106 us; speedup vs baseline: 1.0637x; 1.0102x over previous
//
#include <hip/hip_runtime.h>
#include <hip/hip_fp16.h>

#define U_N 50000
#define I_N 25000
#define D_N 128
#define N_N (U_N + I_N)

#define ROWS_PER_B 128
#define NBUCK 586                       // 75008/128 exactly; bucket = src>>7
#define NBLK 512                        // partition blocks (2 per CU)
#define SN (NBUCK * NBLK)               // 300032 scan elements

#define SCAN_ELEMS_PER_BLOCK 1024       // 256 threads x int4
#define NUM_SCAN_BLOCKS ((SN + SCAN_ELEMS_PER_BLOCK - 1) / SCAN_ELEMS_PER_BLOCK)  // 293
#define SN_PAD (NUM_SCAN_BLOCKS * SCAN_ELEMS_PER_BLOCK)                            // 300032 (==SN)

typedef float f4v __attribute__((ext_vector_type(4)));
typedef float f2v __attribute__((ext_vector_type(2)));
typedef unsigned int u2v __attribute__((ext_vector_type(2)));

// ---- Pass A: per-block coarse histogram (586 buckets) ----
__global__ __launch_bounds__(256) void part_hist_kernel(const int* __restrict__ src,
                                                        int* __restrict__ hist,
                                                        int E, int chunk) {
    __shared__ int h[NBUCK];
    int t = threadIdx.x;
    for (int i = t; i < NBUCK; i += 256) h[i] = 0;
    __syncthreads();
    int b = blockIdx.x;
    int s = b * chunk;
    int e = min(E, s + chunk);
    for (int i = s + t; i < e; i += 256)
        atomicAdd(&h[src[i] >> 7], 1);
    __syncthreads();
    for (int i = t; i < NBUCK; i += 256)
        hist[i * NBLK + b] = h[i];       // bucket-major layout for the scan
#if SN_PAD > SN
    if (b == 0)
        for (int i = SN + t; i < SN_PAD; i += 256) hist[i] = 0;
#endif
}

// -------- scan phase A: per-block sums (1024 elems / block) --------
__global__ __launch_bounds__(256) void block_sums_kernel(const int4* __restrict__ cnt4,
                                                         int* __restrict__ bsums) {
    int t = threadIdx.x;
    int idx = blockIdx.x * 256 + t;
    int4 v = cnt4[idx];
    int s = v.x + v.y + v.z + v.w;
    for (int off = 32; off; off >>= 1) s += __shfl_down(s, off);
    __shared__ int wsum[4];
    int wid = t >> 6, lane = t & 63;
    if (lane == 0) wsum[wid] = s;
    __syncthreads();
    if (t == 0) bsums[blockIdx.x] = wsum[0] + wsum[1] + wsum[2] + wsum[3];
}

// -------- scan phase B: scan the 293 block sums (one block, 512-wide) --------
__global__ __launch_bounds__(512) void scan_bsums_kernel(const int* __restrict__ bsums,
                                                         int* __restrict__ boffs, int nb) {
    __shared__ int sd[512];
    int t = threadIdx.x;
    int v = (t < nb) ? bsums[t] : 0;
    sd[t] = v;
    __syncthreads();
    for (int off = 1; off < 512; off <<= 1) {
        int add = (t >= off) ? sd[t - off] : 0;
        __syncthreads();
        sd[t] += add;
        __syncthreads();
    }
    if (t < nb) boffs[t] = sd[t] - v;   // exclusive
}

// -------- scan phase C: local scan + writeback of exclusive offsets --------
__global__ __launch_bounds__(256) void local_scan_offs_kernel(const int4* __restrict__ cnt4,
                                                              const int* __restrict__ boffs,
                                                              int4* __restrict__ offs4) {
    int t = threadIdx.x;
    int gidx = blockIdx.x * 256 + t;
    int4 v = cnt4[gidx];
    int p0 = v.x, p1 = p0 + v.y, p2 = p1 + v.z, p3 = p2 + v.w;
    int tsum = p3;
    int lane = t & 63, wid = t >> 6;
    int incl = tsum;
    for (int off = 1; off < 64; off <<= 1) {
        int u = __shfl_up(incl, off);
        if (lane >= off) incl += u;
    }
    int lexcl = incl - tsum;
    __shared__ int wsum[4];
    if (lane == 63) wsum[wid] = incl;
    __syncthreads();
    int woff = 0;
    for (int w = 0; w < wid; ++w) woff += wsum[w];
    int base = boffs[blockIdx.x] + woff + lexcl;
    int4 o;
    o.x = base; o.y = base + p0; o.z = base + p1; o.w = base + p2;
    offs4[gidx] = o;
}

// ---- Pass C: partition packed (srcLow7 | dst) into bucket-contiguous runs ----
__global__ __launch_bounds__(256) void partition_kernel(const int* __restrict__ src,
                                                        const int* __restrict__ dst,
                                                        const int* __restrict__ offs,
                                                        unsigned int* __restrict__ part,
                                                        int E, int chunk) {
    __shared__ int c[NBUCK];
    int t = threadIdx.x;
    int b = blockIdx.x;
    for (int i = t; i < NBUCK; i += 256) c[i] = offs[i * NBLK + b];
    __syncthreads();
    int s = b * chunk;
    int e = min(E, s + chunk);
    for (int i = s + t; i < e; i += 256) {
        int sv = src[i];
        int dv = dst[i];
        int pos = atomicAdd(&c[sv >> 7], 1);
        part[pos] = ((unsigned int)(sv & 127) << 24) | (unsigned int)dv;  // dv < 2^24
    }
}

// ---- Pass D: per-bucket fine CSR build (128 rows per bucket, 586 blocks) ----
__global__ __launch_bounds__(256) void bucket_csr_kernel(
    const unsigned int* __restrict__ part, const int* __restrict__ offs,
    int* __restrict__ row_ptr, float* __restrict__ dinv, int* __restrict__ csr_dst,
    int E) {
    int B = blockIdx.x;                  // 0..585
    int t = threadIdx.x;
    int bstart = offs[B * NBLK];
    int bend = (B + 1 < NBUCK) ? offs[(B + 1) * NBLK] : E;
    __shared__ int cnt_s[ROWS_PER_B];
    __shared__ int base_s[ROWS_PER_B];
    __shared__ int wsum[4];
    if (t < ROWS_PER_B) cnt_s[t] = 0;
    __syncthreads();
    for (int i = bstart + t; i < bend; i += 256)
        atomicAdd(&cnt_s[part[i] >> 24], 1);
    __syncthreads();
    int lane = t & 63, wid = t >> 6;
    int v = (t < ROWS_PER_B) ? cnt_s[t] : 0;
    int incl = v;
    for (int off = 1; off < 64; off <<= 1) {
        int u = __shfl_up(incl, off);
        if (lane >= off) incl += u;
    }
    if (lane == 63) wsum[wid] = incl;
    __syncthreads();
    int woff = 0;
    for (int w = 0; w < wid; ++w) woff += wsum[w];   // only wsum[0] matters (wid<2 used)
    int excl = woff + incl - v;
    if (t < ROWS_PER_B) {
        int gid = B * ROWS_PER_B + t;
        float dv = (v > 0) ? rsqrtf((float)v) : 0.0f;
        if (gid <= N_N) row_ptr[gid] = bstart + excl;   // row 75000 gets E naturally
        if (gid < N_N)  dinv[gid] = dv;
        base_s[t] = bstart + excl;
    }
    __syncthreads();
    if (t < ROWS_PER_B) cnt_s[t] = 0;    // reuse as fill counters
    __syncthreads();
    for (int i = bstart + t; i < bend; i += 256) {
        unsigned int ev = part[i];
        int lr = ev >> 24;
        int pos = base_s[lr] + atomicAdd(&cnt_s[lr], 1);
        csr_dst[pos] = (int)(ev & 0xFFFFFFu);
    }
}

// -- init (standalone, R6-verified): x0' = dinv .* concat(ue,ie) in fp16 --
__global__ __launch_bounds__(256) void init_kernel(const f4v* __restrict__ ue,
                                                   const f4v* __restrict__ ie,
                                                   const float* __restrict__ dinv,
                                                   __half2* __restrict__ x) {
    const int NU4 = U_N * D_N / 4;
    const int NT4 = N_N * D_N / 4;
    int i = blockIdx.x * blockDim.x + threadIdx.x;
    if (i >= NT4) return;
    f4v v = (i < NU4) ? ue[i] : ie[i - NU4];
    float di = dinv[i >> 5];            // 128 floats/row = 32 float4/row
    __half2 h0 = __floats2half2_rn(di * v.x, di * v.y);
    __half2 h1 = __floats2half2_rn(di * v.z, di * v.w);
    u2v uu = { __builtin_bit_cast(unsigned int, h0),
               __builtin_bit_cast(unsigned int, h1) };
    *(u2v*)(x + 2 * (size_t)i) = uu;
}

// ------- mid SpMM: one wave per row, unroll 16/8/1 (R8-verified, untouched) -------
// xnext'_i = dinv_i^2 * sum_j x'_j
__global__ __launch_bounds__(256) void spmm_mid_kernel(const __half2* __restrict__ x,
                                                       __half2* __restrict__ xn,
                                                       const float* __restrict__ dinv,
                                                       const int* __restrict__ row_ptr,
                                                       const int* __restrict__ csr_dst) {
    int row = (int)((blockIdx.x * blockDim.x + threadIdx.x) >> 6);
    int lane = threadIdx.x & 63;
    int beg = __builtin_amdgcn_readfirstlane(row_ptr[row]);
    int end = __builtin_amdgcn_readfirstlane(row_ptr[row + 1]);
    float di = dinv[row];
    const __half2* xc = x + lane;       // row j lives at half2 offset j*64
    float accx = 0.0f, accy = 0.0f;
    int k = beg;
    for (; k + 16 <= end; k += 16) {
        int j[16];
        #pragma unroll
        for (int u = 0; u < 16; ++u) j[u] = csr_dst[k + u];
        #pragma unroll
        for (int u = 0; u < 16; ++u) {
            float2 f = __half22float2(xc[(size_t)j[u] * 64]);
            accx += f.x; accy += f.y;
        }
    }
    for (; k + 8 <= end; k += 8) {
        int j[8];
        #pragma unroll
        for (int u = 0; u < 8; ++u) j[u] = csr_dst[k + u];
        #pragma unroll
        for (int u = 0; u < 8; ++u) {
            float2 f = __half22float2(xc[(size_t)j[u] * 64]);
            accx += f.x; accy += f.y;
        }
    }
    for (; k < end; ++k) {
        float2 f = __half22float2(xc[(size_t)csr_dst[k] * 64]);
        accx += f.x; accy += f.y;
    }
    float s = di * di;
    __half2 h = __floats2half2_rn(s * accx, s * accy);
    *(unsigned int*)(xn + (size_t)row * 64 + lane) = __builtin_bit_cast(unsigned int, h);
}

// ------- final SpMM (R8-verified, untouched): y3 + fused average -------
// avg = 0.25*( (x0'+x1'+x2')/dinv + y3 ),  y3 = dinv * sum_j x2'_j
// deg-0 rows: avg = 0.25 * x0 read exactly from ue/ie.
__global__ __launch_bounds__(256) void spmm_final_kernel(const __half2* __restrict__ x2p,
                                                         const __half2* __restrict__ x1p,
                                                         const __half2* __restrict__ x0p,
                                                         const float* __restrict__ ue,
                                                         const float* __restrict__ ie,
                                                         float* __restrict__ avg,
                                                         const float* __restrict__ dinv,
                                                         const int* __restrict__ row_ptr,
                                                         const int* __restrict__ csr_dst) {
    int row = (int)((blockIdx.x * blockDim.x + threadIdx.x) >> 6);
    int lane = threadIdx.x & 63;
    int beg = __builtin_amdgcn_readfirstlane(row_ptr[row]);
    int end = __builtin_amdgcn_readfirstlane(row_ptr[row + 1]);
    float di = dinv[row];
    const __half2* xc = x2p + lane;
    float accx = 0.0f, accy = 0.0f;
    int k = beg;
    for (; k + 16 <= end; k += 16) {
        int j[16];
        #pragma unroll
        for (int u = 0; u < 16; ++u) j[u] = csr_dst[k + u];
        #pragma unroll
        for (int u = 0; u < 16; ++u) {
            float2 f = __half22float2(xc[(size_t)j[u] * 64]);
            accx += f.x; accy += f.y;
        }
    }
    for (; k + 8 <= end; k += 8) {
        int j[8];
        #pragma unroll
        for (int u = 0; u < 8; ++u) j[u] = csr_dst[k + u];
        #pragma unroll
        for (int u = 0; u < 8; ++u) {
            float2 f = __half22float2(xc[(size_t)j[u] * 64]);
            accx += f.x; accy += f.y;
        }
    }
    for (; k < end; ++k) {
        float2 f = __half22float2(xc[(size_t)csr_dst[k] * 64]);
        accx += f.x; accy += f.y;
    }
    f2v a;
    size_t ro = (size_t)row * 64 + lane;
    if (di > 0.0f) {
        float rs = 1.0f / di;
        float2 q0 = __half22float2(x0p[ro]);
        float2 q1 = __half22float2(x1p[ro]);
        float2 q2 = __half22float2(x2p[ro]);
        a.x = 0.25f * (rs * (q0.x + q1.x + q2.x) + di * accx);
        a.y = 0.25f * (rs * (q0.y + q1.y + q2.y) + di * accy);
    } else {
        const float* x0r = (row < U_N) ? (ue + (size_t)row * D_N)
                                       : (ie + (size_t)(row - U_N) * D_N);
        f2v v = *(const f2v*)(x0r + lane * 2);
        a.x = 0.25f * v.x;
        a.y = 0.25f * v.y;
    }
    __builtin_nontemporal_store(a, (f2v*)(avg + (size_t)row * D_N + lane * 2));
}

extern "C" void kernel_launch(void* const* d_in, const int* in_sizes, int n_in,
                              void* d_out, int out_size, void* d_ws, size_t ws_size,
                              hipStream_t stream) {
    const float* ue  = (const float*)d_in[0];
    const float* ie  = (const float*)d_in[1];
    const int* esrc  = (const int*)d_in[2];
    const int* edst  = (const int*)d_in[3];
    float* avg = (float*)d_out;
    const int E = in_sizes[2];
    const int N = N_N;

    // ---- workspace carve-up ----
    char* ws = (char*)d_ws;
    size_t off = 0;
    auto alloc = [&](size_t bytes) -> void* {
        void* p = (void*)(ws + off);
        off += bytes;
        off = (off + 255) & ~((size_t)255);
        return p;
    };
    __half2* x0     = (__half2*)alloc((size_t)N * D_N * sizeof(__half));
    __half2* x1     = (__half2*)alloc((size_t)N * D_N * sizeof(__half));
    __half2* x2     = (__half2*)alloc((size_t)N * D_N * sizeof(__half));
    int*   hist     = (int*)  alloc((size_t)SN_PAD * sizeof(int));
    int*   offs     = (int*)  alloc((size_t)SN_PAD * sizeof(int));
    int*   row_ptr  = (int*)  alloc((size_t)(N + 1) * sizeof(int));
    float* dinv     = (float*)alloc((size_t)N * sizeof(float));
    int*   bsums    = (int*)  alloc((size_t)NUM_SCAN_BLOCKS * sizeof(int));
    int*   boffs    = (int*)  alloc((size_t)NUM_SCAN_BLOCKS * sizeof(int));
    unsigned int* part = (unsigned int*)alloc((size_t)E * sizeof(unsigned int));
    int*   csr_dst  = (int*)  alloc((size_t)E * sizeof(int));

    // ---- build CSR via two-level radix partition ----
    int chunk = (E + NBLK - 1) / NBLK;
    part_hist_kernel<<<NBLK, 256, 0, stream>>>(esrc, hist, E, chunk);
    block_sums_kernel<<<NUM_SCAN_BLOCKS, 256, 0, stream>>>((const int4*)hist, bsums);
    scan_bsums_kernel<<<1, 512, 0, stream>>>(bsums, boffs, NUM_SCAN_BLOCKS);
    local_scan_offs_kernel<<<NUM_SCAN_BLOCKS, 256, 0, stream>>>((const int4*)hist, boffs,
                                                                (int4*)offs);
    partition_kernel<<<NBLK, 256, 0, stream>>>(esrc, edst, offs, part, E, chunk);
    bucket_csr_kernel<<<NBUCK, 256, 0, stream>>>(part, offs, row_ptr, dinv, csr_dst, E);

    // ---- init x0' with full-device parallelism ----
    const int NT4 = N * D_N / 4;
    init_kernel<<<(NT4 + 255) / 256, 256, 0, stream>>>(
        (const f4v*)ue, (const f4v*)ie, dinv, x0);

    // ---- layers: one wave per row ----
    int sblocks = (N * 64) / 256;   // 18750, exact
    spmm_mid_kernel<<<sblocks, 256, 0, stream>>>(x0, x1, dinv, row_ptr, csr_dst);
    spmm_mid_kernel<<<sblocks, 256, 0, stream>>>(x1, x2, dinv, row_ptr, csr_dst);
    spmm_final_kernel<<<sblocks, 256, 0, stream>>>(x2, x1, x0, ue, ie, avg, dinv,
                                                   row_ptr, csr_dst);
}